// Round 2
// baseline (4066.847 us; speedup 1.0000x reference)
//
#include <hip/hip_runtime.h>
#include <stdint.h>

typedef unsigned short u16;
typedef short s16x8 __attribute__((ext_vector_type(8)));
typedef float f32x4 __attribute__((ext_vector_type(4)));

#define DEV __device__ __forceinline__

DEV float bf2f(u16 h){ union{uint32_t u; float f;} x; x.u = ((uint32_t)h)<<16; return x.f; }
DEV u16 f2bf(float f){ union{float f; uint32_t u;} x; x.f = f; uint32_t u = x.u;
  return (u16)((u + 0x7fffu + ((u>>16)&1u))>>16); }

DEV float tanh_fast(float x){
  x = fminf(3.2f, fmaxf(-3.2f, x));
  float s = x*x;
  float n = x * fmaf(s, fmaf(s, (s + 378.0f), 17325.0f), 135135.0f);
  float d = fmaf(s, fmaf(s, fmaf(s, 28.0f, 3150.0f), 62370.0f), 135135.0f);
  return __fdividef(n, d);
}
DEV float sigmoid_fast(float x){ return __fdividef(1.0f, 1.0f + __expf(-x)); }

// ---------------- f32 -> bf16 bulk convert (n % 4 == 0) ----------------
__global__ void f2b_kernel(const float* __restrict__ src, u16* __restrict__ dst, int n4){
  int i = blockIdx.x*blockDim.x + threadIdx.x;
  if (i < n4) {
    float4 v = ((const float4*)src)[i];
    ushort4 o; o.x = f2bf(v.x); o.y = f2bf(v.y); o.z = f2bf(v.z); o.w = f2bf(v.w);
    ((ushort4*)dst)[i] = o;
  }
}

// ---------------- generic C = A * B^T (+bias) bf16 MFMA GEMM ----------------
// A: M x K bf16 (lda), B: N x K bf16 (ldb). M % 64 == 0, K % 64 == 0. N guarded.
// mode 0: f32 out; 1: bf16 out; 2: f32 out with row remap (r=s*64+b -> b*31+s)
__global__ __launch_bounds__(256) void gemm_bt(
    const u16* __restrict__ A, int lda,
    const u16* __restrict__ B, int ldb,
    const float* __restrict__ bias1, const float* __restrict__ bias2,
    void* __restrict__ C, int ldc,
    int M, int N, int K, int Mt, int mode)
{
  __shared__ __align__(16) u16 As[64*64];
  __shared__ __align__(16) u16 Bs[128*64];
  int mt = blockIdx.x % Mt, nt = blockIdx.x / Mt;
  int m0 = mt*64, n0 = nt*128;
  int tid = threadIdx.x, wave = tid>>6, lane = tid&63;
  int lrow = lane>>3, lcol = (lane&7)*8;
  f32x4 acc[2][4];
  #pragma unroll
  for (int i=0;i<2;i++)
    #pragma unroll
    for (int j=0;j<4;j++) acc[i][j] = (f32x4){0,0,0,0};
  int wm = (wave>>1)*32, wn = (wave&1)*64;
  int fr = lane&15, fk = (lane>>4)*8;
  for (int k0 = 0; k0 < K; k0 += 64) {
    __syncthreads();
    #pragma unroll
    for (int i = 0; i < 2; i++) {
      int ci = wave + i*4;
      int row = ci*8 + lrow;
      const u16* g = A + (size_t)(m0+row)*lda + k0 + lcol;
      __builtin_amdgcn_global_load_lds(
        (const __attribute__((address_space(1))) uint32_t*)g,
        (__attribute__((address_space(3))) uint32_t*)&As[ci*512], 16, 0, 0);
    }
    #pragma unroll
    for (int i = 0; i < 4; i++) {
      int ci = wave + i*4;
      int row = ci*8 + lrow;
      int gr = n0 + row; gr = gr < N ? gr : N-1;
      const u16* g = B + (size_t)gr*ldb + k0 + lcol;
      __builtin_amdgcn_global_load_lds(
        (const __attribute__((address_space(1))) uint32_t*)g,
        (__attribute__((address_space(3))) uint32_t*)&Bs[ci*512], 16, 0, 0);
    }
    __syncthreads();
    #pragma unroll
    for (int kk = 0; kk < 2; kk++) {
      s16x8 af[2], bfv[4];
      #pragma unroll
      for (int mi=0; mi<2; mi++)
        af[mi] = *(const s16x8*)&As[(wm + mi*16 + fr)*64 + kk*32 + fk];
      #pragma unroll
      for (int ni=0; ni<4; ni++)
        bfv[ni] = *(const s16x8*)&Bs[(wn + ni*16 + fr)*64 + kk*32 + fk];
      #pragma unroll
      for (int mi=0; mi<2; mi++)
        #pragma unroll
        for (int ni=0; ni<4; ni++)
          acc[mi][ni] = __builtin_amdgcn_mfma_f32_16x16x32_bf16(af[mi], bfv[ni], acc[mi][ni], 0,0,0);
    }
  }
  #pragma unroll
  for (int mi=0; mi<2; mi++)
    #pragma unroll
    for (int ni=0; ni<4; ni++) {
      int col = n0 + wn + ni*16 + (lane&15);
      if (col >= N) continue;
      float bv = 0.0f;
      if (bias1) bv += bias1[col];
      if (bias2) bv += bias2[col];
      int rbase = m0 + wm + mi*16 + ((lane>>4)<<2);
      #pragma unroll
      for (int r=0; r<4; r++) {
        int row = rbase + r;
        float v = acc[mi][ni][r] + bv;
        if (mode == 0) ((float*)C)[(size_t)row*ldc + col] = v;
        else if (mode == 1) ((u16*)C)[(size_t)row*ldc + col] = f2bf(v);
        else { int orow = (row&63)*31 + (row>>6); ((float*)C)[(size_t)orow*ldc + col] = v; }
      }
    }
}

// ---------- token embedding gather: X[s*64+b][e] = bf16(embed[y[b][s]][e]) ----------
__global__ void gather_x(const int* __restrict__ y, const float* __restrict__ embed, u16* __restrict__ X)
{
  int r = blockIdx.x;
  int s = r>>6, b = r&63;
  int tok = y[b*32 + s];
  X[(size_t)r*256 + threadIdx.x] = f2bf(embed[(size_t)tok*256 + threadIdx.x]);
}

// ---------------- persistent recurrence kernel ----------------
#define NB 144

DEV void gbar(unsigned* bar){
  __syncthreads();
  if (threadIdx.x == 0) {
    __threadfence();
    unsigned g = __hip_atomic_load(&bar[1], __ATOMIC_RELAXED, __HIP_MEMORY_SCOPE_AGENT);
    unsigned a = __hip_atomic_fetch_add(&bar[0], 1u, __ATOMIC_ACQ_REL, __HIP_MEMORY_SCOPE_AGENT);
    if (a == (unsigned)(NB-1)) {
      __hip_atomic_store(&bar[0], 0u, __ATOMIC_RELAXED, __HIP_MEMORY_SCOPE_AGENT);
      __hip_atomic_fetch_add(&bar[1], 1u, __ATOMIC_RELEASE, __HIP_MEMORY_SCOPE_AGENT);
    } else {
      while (__hip_atomic_load(&bar[1], __ATOMIC_ACQUIRE, __HIP_MEMORY_SCOPE_AGENT) == g) {
        __builtin_amdgcn_s_sleep(2);
      }
    }
    __threadfence();
  }
  __syncthreads();
}

__global__ __launch_bounds__(256) void decoder_steps(
    const float* __restrict__ V,     // (64,196,128) f32
    const u16* __restrict__ attWwB,  // (256,512) bf16 (converted)
    const float* __restrict__ attWb, // (256) f32
    const float* __restrict__ attvw, // (256) f32
    const float* __restrict__ attvb, // (1) f32
    const u16* __restrict__ WihB,    // (2048,384) bf16 (converted)
    const u16* __restrict__ WhhB,    // (2048,512) bf16 (converted)
    u16* __restrict__ H,             // (32,64,512) bf16, slot0 zeroed
    const u16* __restrict__ UV,      // (64,196,256) bf16
    const float* __restrict__ Xg,    // (31,64,2048) f32 (x-part + biases)
    float* __restrict__ gh,          // (64,2048)
    float* __restrict__ wh,          // (64,256)
    float* __restrict__ cp,          // (2,64,128)
    float* __restrict__ mp,          // (2,64)
    float* __restrict__ sp,          // (2,64)
    unsigned* __restrict__ bar)
{
  int bid = blockIdx.x, tid = threadIdx.x;
  int wave = tid>>6, lane = tid&63;
  __shared__ float whs[256];
  __shared__ float vws[256];
  __shared__ float e2[2][128];
  __shared__ float esc[128];
  __shared__ float red[2];
  __shared__ float a0s[64], a1s[64];
  __shared__ __align__(16) u16 ctxs[64*128];

  float c_reg[4] = {0.f,0.f,0.f,0.f};
  float vb = attvb[0];

  for (int t = 0; t < 31; t++) {
    // ---- P1: [gh | Wh] = h @ [W_hh ; att_W_w]^T (+Xg | +att_W_b) ----
    {
      int tile = bid;
      const u16* Bsrc = (tile < 128) ? (WhhB + (size_t)tile*16*512)
                                     : (attWwB + (size_t)(tile-128)*16*512);
      const u16* Asrc = H + (size_t)t*32768;
      int arow = wave*16 + (lane&15);
      int brow = lane&15;
      int fk = (lane>>4)*8;
      f32x4 acc = (f32x4){0,0,0,0};
      #pragma unroll 4
      for (int ks = 0; ks < 16; ks++) {
        int kidx = ks*32 + fk;
        s16x8 af = *(const s16x8*)&Asrc[(size_t)arow*512 + kidx];
        s16x8 bf = *(const s16x8*)&Bsrc[(size_t)brow*512 + kidx];
        acc = __builtin_amdgcn_mfma_f32_16x16x32_bf16(af, bf, acc, 0,0,0);
      }
      int col = lane&15;
      int rb = wave*16 + ((lane>>4)<<2);
      if (tile < 128) {
        int j = tile*16 + col;
        #pragma unroll
        for (int r=0;r<4;r++){
          int b = rb + r;
          gh[b*2048 + j] = acc[r] + Xg[((size_t)t*64 + b)*2048 + j];
        }
      } else {
        int a = (tile-128)*16 + col;
        float wbv = attWb[a];
        #pragma unroll
        for (int r=0;r<4;r++){
          int b = rb + r;
          wh[b*256 + a] = acc[r] + wbv;
        }
      }
    }
    gbar(bar);
    // ---- P2: attention (2 blocks per batch element, split over n) ----
    if (bid < 128) {
      int b = bid>>1, half = bid&1;
      whs[tid] = wh[b*256 + tid];
      vws[tid] = attvw[tid];
      __syncthreads();
      if (tid < 196) {
        int nidx = tid>>1, ah = tid&1;
        int n = half*98 + nidx;
        const u16* uvrow = UV + (((size_t)b*196 + n)<<8) + ah*128;
        float e = 0.0f;
        #pragma unroll 2
        for (int a8 = 0; a8 < 128; a8 += 8) {
          s16x8 u8 = *(const s16x8*)&uvrow[a8];
          #pragma unroll
          for (int j=0;j<8;j++){
            int a = ah*128 + a8 + j;
            e = fmaf(vws[a], tanh_fast(whs[a] + bf2f((u16)u8[j])), e);
          }
        }
        e2[ah][nidx] = e;
      }
      __syncthreads();
      if (tid < 98) esc[tid] = e2[0][tid] + e2[1][tid] + vb;
      __syncthreads();
      if (tid < 64) {
        float m = -1e30f;
        for (int i=tid;i<98;i+=64) m = fmaxf(m, esc[i]);
        #pragma unroll
        for (int off=32; off>=1; off>>=1) m = fmaxf(m, __shfl_xor(m, off));
        if (tid==0) red[0] = m;
      }
      __syncthreads();
      float mx = red[0];
      if (tid < 98) esc[tid] = __expf(esc[tid] - mx);
      __syncthreads();
      if (tid < 64) {
        float s = 0.f;
        for (int i=tid;i<98;i+=64) s += esc[i];
        #pragma unroll
        for (int off=32; off>=1; off>>=1) s += __shfl_xor(s, off);
        if (tid==0) { mp[half*64+b] = mx; sp[half*64+b] = s; }
      }
      __syncthreads();
      if (tid < 128) {
        float a = 0.f;
        const float* vbase = V + (((size_t)b*196 + half*98)<<7) + tid;
        for (int n=0;n<98;n++) a = fmaf(esc[n], vbase[(size_t)n*128], a);
        cp[((size_t)half*64 + b)*128 + tid] = a;
      }
    }
    gbar(bar);
    // ---- P3: combine softmax halves, ctx-gates GEMM, LSTM pointwise ----
    if (bid < 32) {
      int k0 = bid*16;
      if (tid < 64) {
        float m0v = mp[tid], m1v = mp[64+tid];
        float s0v = sp[tid], s1v = sp[64+tid];
        float m = fmaxf(m0v, m1v);
        float w0 = __expf(m0v - m), w1 = __expf(m1v - m);
        float inv = __fdividef(1.0f, w0*s0v + w1*s1v);
        a0s[tid] = w0*inv; a1s[tid] = w1*inv;
      }
      __syncthreads();
      for (int idx = tid; idx < 8192; idx += 256) {
        int b = idx>>7, k = idx&127;
        ctxs[idx] = f2bf(a0s[b]*cp[(size_t)b*128 + k] + a1s[b]*cp[(size_t)(64+b)*128 + k]);
      }
      __syncthreads();
      f32x4 acc[4];
      #pragma unroll
      for (int g=0; g<4; g++) acc[g] = (f32x4){0,0,0,0};
      int fr = lane&15, fk = (lane>>4)*8;
      #pragma unroll
      for (int ks=0; ks<4; ks++) {
        int kidx = ks*32 + fk;
        s16x8 af = *(const s16x8*)&ctxs[(wave*16 + fr)*128 + kidx];
        #pragma unroll
        for (int g=0; g<4; g++) {
          int jrow = g*512 + k0 + fr;
          s16x8 bf = *(const s16x8*)&WihB[(size_t)jrow*384 + 256 + kidx];
          acc[g] = __builtin_amdgcn_mfma_f32_16x16x32_bf16(af, bf, acc[g], 0,0,0);
        }
      }
      int k = k0 + (lane&15);
      int rb = wave*16 + ((lane>>4)<<2);
      u16* Hn = H + (size_t)(t+1)*32768;
      #pragma unroll
      for (int r=0;r<4;r++) {
        int b = rb + r;
        float xi = acc[0][r] + gh[b*2048 + k];
        float xf = acc[1][r] + gh[b*2048 + 512 + k];
        float xg = acc[2][r] + gh[b*2048 + 1024 + k];
        float xo = acc[3][r] + gh[b*2048 + 1536 + k];
        float ig = sigmoid_fast(xi), fg = sigmoid_fast(xf), og = sigmoid_fast(xo);
        float gg = tanh_fast(xg);
        float c = fg*c_reg[r] + ig*gg;
        c_reg[r] = c;
        Hn[(size_t)b*512 + k] = f2bf(og * tanh_fast(c));
      }
    }
    gbar(bar);
  }
}

// ---------------- workspace offsets (bytes, 256-aligned) ----------------
#define OFF_BAR 0u
#define OFF_H    256u            // 2,097,152  bf16 (32,64,512)
#define OFF_UV   2097408u        // 6,422,528  bf16 (64,196,256)
#define OFF_X    8519936u        // 1,015,808  bf16 (1984,256)
#define OFF_XG   9535744u        // 16,252,928 f32  (31,64,2048)
#define OFF_GH   25788672u       // 524,288    f32  (64,2048)
#define OFF_WH   26312960u       // 65,536     f32  (64,256)
#define OFF_CP   26378496u       // 65,536     f32  (2,64,128)
#define OFF_MS   26444032u       // 512
#define OFF_SS   26444544u       // 512
#define OFF_E    26445056u       // 1,015,808  bf16 (1984,256)
#define OFF_VB   27460864u       // 3,211,264  bf16 V
#define OFF_EMB  30672128u       // 15,360,000 bf16 embed
#define OFF_WIH  46032128u       // 1,572,864  bf16 Wih
#define OFF_WHH  47604992u       // 2,097,152  bf16 Whh
#define OFF_AWW  49702144u       // 262,144    bf16 attWw
#define OFF_AUW  49964288u       // 65,536     bf16 attUw
#define OFF_PRJ  50029824u       // 262,144    bf16 projw  -> end 50,291,968

extern "C" void kernel_launch(void* const* d_in, const int* in_sizes, int n_in,
                              void* d_out, int out_size, void* d_ws, size_t ws_size,
                              hipStream_t stream)
{
  const float* V      = (const float*)d_in[0];
  const int*   y      = (const int*)  d_in[1];
  const float* embed  = (const float*)d_in[2];
  const float* attWw  = (const float*)d_in[3];
  const float* attWb  = (const float*)d_in[4];
  const float* attUw  = (const float*)d_in[5];
  const float* attUb  = (const float*)d_in[6];
  const float* attvw  = (const float*)d_in[7];
  const float* attvb  = (const float*)d_in[8];
  const float* Wih    = (const float*)d_in[9];
  const float* Whh    = (const float*)d_in[10];
  const float* bih    = (const float*)d_in[11];
  const float* bhh    = (const float*)d_in[12];
  const float* projw  = (const float*)d_in[13];
  float* out = (float*)d_out;
  char* ws = (char*)d_ws;

  unsigned* bar = (unsigned*)(ws + OFF_BAR);
  u16*   H    = (u16*)  (ws + OFF_H);
  u16*   UVb  = (u16*)  (ws + OFF_UV);
  u16*   Xb   = (u16*)  (ws + OFF_X);
  float* Xg   = (float*)(ws + OFF_XG);
  float* gh   = (float*)(ws + OFF_GH);
  float* wh   = (float*)(ws + OFF_WH);
  float* cp   = (float*)(ws + OFF_CP);
  float* mp   = (float*)(ws + OFF_MS);
  float* sp   = (float*)(ws + OFF_SS);
  u16*   E    = (u16*)  (ws + OFF_E);
  u16*   Vb   = (u16*)  (ws + OFF_VB);
  u16*   embB = (u16*)  (ws + OFF_EMB);
  u16*   WihB = (u16*)  (ws + OFF_WIH);
  u16*   WhhB = (u16*)  (ws + OFF_WHH);
  u16*   attWwB = (u16*)(ws + OFF_AWW);
  u16*   attUwB = (u16*)(ws + OFF_AUW);
  u16*   projB  = (u16*)(ws + OFF_PRJ);

  // zero barrier + H slot 0 (h0 = 0) — re-done every call (ws is re-poisoned)
  hipMemsetAsync(ws, 0, 256 + 65536, stream);

  // f32 -> bf16 conversions for MFMA operands
  f2b_kernel<<<(401408+255)/256, 256, 0, stream>>>(V,     Vb,     401408);  // 64*196*128/4
  f2b_kernel<<<(1920000+255)/256,256, 0, stream>>>(embed, embB,  1920000);  // 30000*256/4
  f2b_kernel<<<(196608+255)/256, 256, 0, stream>>>(Wih,   WihB,   196608);  // 2048*384/4
  f2b_kernel<<<(262144+255)/256, 256, 0, stream>>>(Whh,   WhhB,   262144);  // 2048*512/4
  f2b_kernel<<<(32768+255)/256,  256, 0, stream>>>(attWw, attWwB,  32768);  // 256*512/4
  f2b_kernel<<<(8192+255)/256,   256, 0, stream>>>(attUw, attUwB,   8192);  // 256*128/4
  f2b_kernel<<<(32768+255)/256,  256, 0, stream>>>(projw, projB,   32768);  // 256*512/4

  gather_x<<<1984, 256, 0, stream>>>(y, embed, Xb);

  // UV = V @ attUw^T + attUb  (bf16 out)   M=12544 N=256 K=128
  gemm_bt<<<196*2, 256, 0, stream>>>(Vb, 128, attUwB, 128, attUb, nullptr,
                                     UVb, 256, 12544, 256, 128, 196, 1);
  // Xg = X @ Wih[:, :256]^T + bih + bhh  (f32 out)   M=1984 N=2048 K=256
  gemm_bt<<<31*16, 256, 0, stream>>>(Xb, 256, WihB, 384, bih, bhh,
                                     Xg, 2048, 1984, 2048, 256, 31, 0);

  decoder_steps<<<NB, 256, 0, stream>>>(V, attWwB, attWb, attvw, attvb,
      WihB, WhhB, H, UVb, Xg, gh, wh, cp, mp, sp, bar);

  // E = H[1..31] @ projw^T (bf16 out)   M=1984 N=256 K=512
  gemm_bt<<<31*2, 256, 0, stream>>>(H + 32768, 512, projB, 512, nullptr, nullptr,
                                    E, 256, 1984, 256, 512, 31, 1);
  // logits = E @ embed^T -> d_out f32 with (s,b)->(b,s) row remap   M=1984 N=30000 K=256
  gemm_bt<<<31*235, 256, 0, stream>>>(E, 256, embB, 256, nullptr, nullptr,
                                      out, 30000, 1984, 30000, 256, 31, 2);
}

// Round 3
// 2815.640 us; speedup vs baseline: 1.4444x; 1.4444x over previous
//
#include <hip/hip_runtime.h>
#include <stdint.h>

typedef unsigned short u16;
typedef uint32_t u32;
typedef short s16x8 __attribute__((ext_vector_type(8)));
typedef float f32x4 __attribute__((ext_vector_type(4)));

#define DEV __device__ __forceinline__

DEV float bf2f(u16 h){ union{u32 u; float f;} x; x.u = ((u32)h)<<16; return x.f; }
DEV u16 f2bf(float f){ union{float f; u32 u;} x; x.f = f; u32 u = x.u;
  return (u16)((u + 0x7fffu + ((u>>16)&1u))>>16); }
DEV float uhi2f(u32 w){ union{u32 u; float f;} x; x.u = w & 0xffff0000u; return x.f; }
DEV float ulo2f(u32 w){ union{u32 u; float f;} x; x.u = w << 16; return x.f; }

DEV float tanh_fast(float x){
  x = fminf(3.2f, fmaxf(-3.2f, x));
  float s = x*x;
  float n = x * fmaf(s, fmaf(s, (s + 378.0f), 17325.0f), 135135.0f);
  float d = fmaf(s, fmaf(s, fmaf(s, 28.0f, 3150.0f), 62370.0f), 135135.0f);
  return __fdividef(n, d);
}
DEV float sigmoid_fast(float x){ return __fdividef(1.0f, 1.0f + __expf(-x)); }

// device-coherent (agent-scope, L2-bypass) accessors
DEV float ld_f(const float* p){ return __hip_atomic_load(p, __ATOMIC_RELAXED, __HIP_MEMORY_SCOPE_AGENT); }
DEV void  st_f(float* p, float v){ __hip_atomic_store(p, v, __ATOMIC_RELAXED, __HIP_MEMORY_SCOPE_AGENT); }
DEV u32   ld_u(const u32* p){ return __hip_atomic_load(p, __ATOMIC_RELAXED, __HIP_MEMORY_SCOPE_AGENT); }
DEV void  st_u(u32* p, u32 v){ __hip_atomic_store(p, v, __ATOMIC_RELAXED, __HIP_MEMORY_SCOPE_AGENT); }

// ---------------- f32 -> bf16 bulk convert (n % 4 == 0) ----------------
__global__ void f2b_kernel(const float* __restrict__ src, u16* __restrict__ dst, int n4){
  int i = blockIdx.x*blockDim.x + threadIdx.x;
  if (i < n4) {
    float4 v = ((const float4*)src)[i];
    ushort4 o; o.x = f2bf(v.x); o.y = f2bf(v.y); o.z = f2bf(v.z); o.w = f2bf(v.w);
    ((ushort4*)dst)[i] = o;
  }
}

// ---- extract Wih[:,256:384] as f32 (2048 x 128), and zero the barrier flags ----
__global__ void prep_wih2f(const float* __restrict__ Wih, float* __restrict__ Wf){
  int idx = blockIdx.x*256 + threadIdx.x;      // 2048*128 = 262144
  int j = idx>>7, k = idx&127;
  Wf[idx] = Wih[(size_t)j*384 + 256 + k];
}

// ---------------- generic C = A * B^T (+bias) bf16 MFMA GEMM ----------------
// mode 0: f32 out; 1: bf16 out; 2: f32 out with row remap (r=s*64+b -> b*31+s)
__global__ __launch_bounds__(256) void gemm_bt(
    const u16* __restrict__ A, int lda,
    const u16* __restrict__ B, int ldb,
    const float* __restrict__ bias1, const float* __restrict__ bias2,
    void* __restrict__ C, int ldc,
    int M, int N, int K, int Mt, int mode)
{
  __shared__ __align__(16) u16 As[64*64];
  __shared__ __align__(16) u16 Bs[128*64];
  int mt = blockIdx.x % Mt, nt = blockIdx.x / Mt;
  int m0 = mt*64, n0 = nt*128;
  int tid = threadIdx.x, wave = tid>>6, lane = tid&63;
  int lrow = lane>>3, lcol = (lane&7)*8;
  f32x4 acc[2][4];
  #pragma unroll
  for (int i=0;i<2;i++)
    #pragma unroll
    for (int j=0;j<4;j++) acc[i][j] = (f32x4){0,0,0,0};
  int wm = (wave>>1)*32, wn = (wave&1)*64;
  int fr = lane&15, fk = (lane>>4)*8;
  for (int k0 = 0; k0 < K; k0 += 64) {
    __syncthreads();
    #pragma unroll
    for (int i = 0; i < 2; i++) {
      int ci = wave + i*4;
      int row = ci*8 + lrow;
      const u16* g = A + (size_t)(m0+row)*lda + k0 + lcol;
      __builtin_amdgcn_global_load_lds(
        (const __attribute__((address_space(1))) u32*)g,
        (__attribute__((address_space(3))) u32*)&As[ci*512], 16, 0, 0);
    }
    #pragma unroll
    for (int i = 0; i < 4; i++) {
      int ci = wave + i*4;
      int row = ci*8 + lrow;
      int gr = n0 + row; gr = gr < N ? gr : N-1;
      const u16* g = B + (size_t)gr*ldb + k0 + lcol;
      __builtin_amdgcn_global_load_lds(
        (const __attribute__((address_space(1))) u32*)g,
        (__attribute__((address_space(3))) u32*)&Bs[ci*512], 16, 0, 0);
    }
    __syncthreads();
    #pragma unroll
    for (int kk = 0; kk < 2; kk++) {
      s16x8 af[2], bfv[4];
      #pragma unroll
      for (int mi=0; mi<2; mi++)
        af[mi] = *(const s16x8*)&As[(wm + mi*16 + fr)*64 + kk*32 + fk];
      #pragma unroll
      for (int ni=0; ni<4; ni++)
        bfv[ni] = *(const s16x8*)&Bs[(wn + ni*16 + fr)*64 + kk*32 + fk];
      #pragma unroll
      for (int mi=0; mi<2; mi++)
        #pragma unroll
        for (int ni=0; ni<4; ni++)
          acc[mi][ni] = __builtin_amdgcn_mfma_f32_16x16x32_bf16(af[mi], bfv[ni], acc[mi][ni], 0,0,0);
    }
  }
  #pragma unroll
  for (int mi=0; mi<2; mi++)
    #pragma unroll
    for (int ni=0; ni<4; ni++) {
      int col = n0 + wn + ni*16 + (lane&15);
      if (col >= N) continue;
      float bv = 0.0f;
      if (bias1) bv += bias1[col];
      if (bias2) bv += bias2[col];
      int rbase = m0 + wm + mi*16 + ((lane>>4)<<2);
      #pragma unroll
      for (int r=0; r<4; r++) {
        int row = rbase + r;
        float v = acc[mi][ni][r] + bv;
        if (mode == 0) ((float*)C)[(size_t)row*ldc + col] = v;
        else if (mode == 1) ((u16*)C)[(size_t)row*ldc + col] = f2bf(v);
        else { int orow = (row&63)*31 + (row>>6); ((float*)C)[(size_t)orow*ldc + col] = v; }
      }
    }
}

// ---------- token embedding gather: X[s*64+b][e] = bf16(embed[y[b][s]][e]) ----------
__global__ void gather_x(const int* __restrict__ y, const float* __restrict__ embed, u16* __restrict__ X)
{
  int r = blockIdx.x;
  int s = r>>6, b = r&63;
  int tok = y[b*32 + s];
  X[(size_t)r*256 + threadIdx.x] = f2bf(embed[(size_t)tok*256 + threadIdx.x]);
}

// ---------------- persistent recurrence kernel (72 blocks, flag barrier) ----------------
#define NB 72

// all-report barrier: no fences, no RMW. Data moves via agent-scope (sc1) accesses,
// so L2 is never written back / invalidated — it stays warm for weights/UV/V/Xg.
DEV void gbar2(u32* flags, int bid, unsigned g){
  __asm__ volatile("" ::: "memory");
  __builtin_amdgcn_s_waitcnt(0);          // all this wave's sc1 stores are at the coherence point
  __syncthreads();                        // -> all waves of the block have drained
  if (threadIdx.x == 0) st_u(&flags[bid], g);
  if (threadIdx.x < 64) {
    bool done = false;
    while (!done) {
      u32 a = ld_u(&flags[threadIdx.x]);
      u32 b = (threadIdx.x < 8) ? ld_u(&flags[64+threadIdx.x]) : g;
      done = __all(a >= g && b >= g);
      if (!done) __builtin_amdgcn_s_sleep(1);
    }
  }
  __syncthreads();
  __asm__ volatile("" ::: "memory");
}

__global__ __launch_bounds__(256) void decoder_steps(
    const float* __restrict__ V,     // (64,196,128) f32, cached
    const float* __restrict__ attWb, // (256) f32, cached
    const float* __restrict__ attvw, // (256) f32, cached
    const float* __restrict__ attvb, // (1)
    const u16* __restrict__ WhhB,    // (2048,512) bf16, cached
    const u16* __restrict__ attWwB,  // (256,512) bf16, cached
    const float* __restrict__ Wf,    // (2048,128) f32 = Wih[:,256:384], cached
    u32* __restrict__ H32,           // (32,64,256) u32 (bf16 pairs), coherent
    const u16* __restrict__ UV,      // (64,196,256) bf16, cached
    const float* __restrict__ Xg,    // (31,64,2048) f32, cached
    float* __restrict__ gh,          // (64,2048) f32, coherent
    float* __restrict__ wh,          // (64,256) f32, coherent
    u32* __restrict__ flags)
{
  int bid = blockIdx.x, tid = threadIdx.x;
  int wave = tid>>6, lane = tid&63;
  int fr = lane&15, fkq = lane>>4;

  __shared__ float whs[256];
  __shared__ float vws[256];
  __shared__ float esc[200];
  __shared__ float red[2];
  __shared__ float part[256];
  __shared__ float ctxf[128];
  __shared__ float hs[512];

  float c_reg[2] = {0.f, 0.f};
  float vb = attvb[0];
  unsigned gen = 0;

  // per-block P1 weight base (block handles 32 consecutive rows of [Whh ; attWw])
  const u16* Wbase = (bid < 64) ? (WhhB + (size_t)bid*32*512)
                                : (attWwB + (size_t)(bid-64)*32*512);

  for (int t = 0; t < 31; t++) {
    // ---- P1: [gh | wh] = h_t @ [W_hh ; att_W_w]^T (+Xg | +att_W_b) ----
    {
      const u32* Hrow = H32 + (size_t)t*16384 + (wave*16 + fr)*256;
      f32x4 acc0 = (f32x4){0,0,0,0}, acc1 = (f32x4){0,0,0,0};
      #pragma unroll 4
      for (int ks = 0; ks < 16; ks++) {
        union { u32 w[4]; s16x8 v; } cvt;
        const u32* ap = Hrow + ks*16 + fkq*4;
        #pragma unroll
        for (int i=0;i<4;i++) cvt.w[i] = ld_u(ap+i);
        s16x8 af = cvt.v;
        int kidx = ks*32 + fkq*8;
        s16x8 b0 = *(const s16x8*)&Wbase[(size_t)(fr)*512 + kidx];
        s16x8 b1 = *(const s16x8*)&Wbase[(size_t)(16+fr)*512 + kidx];
        acc0 = __builtin_amdgcn_mfma_f32_16x16x32_bf16(af, b0, acc0, 0,0,0);
        acc1 = __builtin_amdgcn_mfma_f32_16x16x32_bf16(af, b1, acc1, 0,0,0);
      }
      int col = lane&15;
      int rb = wave*16 + fkq*4;
      if (bid < 64) {
        #pragma unroll
        for (int ntile=0; ntile<2; ntile++) {
          int j = bid*32 + ntile*16 + col;
          f32x4 a = ntile ? acc1 : acc0;
          #pragma unroll
          for (int r=0;r<4;r++){
            int b = rb + r;
            st_f(&gh[b*2048 + j], a[r] + Xg[((size_t)t*64 + b)*2048 + j]);
          }
        }
      } else {
        #pragma unroll
        for (int ntile=0; ntile<2; ntile++) {
          int a_ = (bid-64)*32 + ntile*16 + col;
          float wbv = attWb[a_];
          f32x4 a = ntile ? acc1 : acc0;
          #pragma unroll
          for (int r=0;r<4;r++){
            int b = rb + r;
            st_f(&wh[b*256 + a_], a[r] + wbv);
          }
        }
      }
    }
    gen++; gbar2(flags, bid, gen);

    // ---- P2': per-batch block: scores -> softmax -> ctx -> ctx-gates -> LSTM pointwise ----
    if (bid < 64) {
      int b = bid;
      // preload gh rows for this thread's 8 gate dims (issued early, used at the end)
      float ghv[8];
      #pragma unroll
      for (int r=0;r<8;r++) ghv[r] = ld_f(&gh[b*2048 + tid + 256*r]);
      whs[tid] = ld_f(&wh[b*256 + tid]);
      vws[tid] = attvw[tid];
      __syncthreads();

      // scores: thread n computes e[n] over 256 attention dims
      if (tid < 196) {
        const u16* uvrow = UV + ((size_t)b*196 + tid)*256;
        float e = 0.0f;
        for (int a8 = 0; a8 < 256; a8 += 8) {
          s16x8 u8 = *(const s16x8*)&uvrow[a8];
          #pragma unroll
          for (int j=0;j<8;j++)
            e = fmaf(vws[a8+j], tanh_fast(whs[a8+j] + bf2f((u16)u8[j])), e);
        }
        esc[tid] = e + vb;
      }
      __syncthreads();
      if (tid < 64) {
        float m = fmaxf(esc[tid], esc[64+tid]);
        if (tid < 68) m = fmaxf(m, esc[128+tid]);
        if (tid < 4)  m = fmaxf(m, esc[192+tid]);
        #pragma unroll
        for (int off=32; off>=1; off>>=1) m = fmaxf(m, __shfl_xor(m, off));
        if (tid==0) red[0] = m;
      }
      __syncthreads();
      float mx = red[0];
      if (tid < 196) esc[tid] = __expf(esc[tid] - mx);
      __syncthreads();
      if (tid < 64) {
        float s = esc[tid] + esc[64+tid];
        if (tid < 68) s += esc[128+tid];
        if (tid < 4)  s += esc[192+tid];
        #pragma unroll
        for (int off=32; off>=1; off>>=1) s += __shfl_xor(s, off);
        if (tid==0) red[1] = s;
      }
      __syncthreads();
      float inv = __fdividef(1.0f, red[1]);

      // ctx: two n-halves in parallel, combine
      {
        int k = tid&127, hf = tid>>7;
        const float* vp = V + ((size_t)b*196 + hf*98)*128 + k;
        float a = 0.f;
        for (int n2=0; n2<98; n2++) a = fmaf(esc[hf*98+n2], vp[(size_t)n2*128], a);
        part[tid] = a;
      }
      __syncthreads();
      if (tid < 128) ctxf[tid] = (part[tid] + part[128+tid]) * inv;
      __syncthreads();

      // ctx-gates: thread handles rows j = tid + 256*r, r=0..7  (f32 weights)
      float acc2[8] = {0,0,0,0,0,0,0,0};
      for (int q0=0; q0<128; q0+=8) {
        float cx[8];
        *(float4*)&cx[0] = *(const float4*)&ctxf[q0];
        *(float4*)&cx[4] = *(const float4*)&ctxf[q0+4];
        #pragma unroll
        for (int r=0;r<8;r++){
          const float4* wp = (const float4*)&Wf[(size_t)(tid+256*r)*128 + q0];
          float4 w0 = wp[0], w1 = wp[1];
          acc2[r] = fmaf(cx[0],w0.x, fmaf(cx[1],w0.y, fmaf(cx[2],w0.z, fmaf(cx[3],w0.w,
                    fmaf(cx[4],w1.x, fmaf(cx[5],w1.y, fmaf(cx[6],w1.z, fmaf(cx[7],w1.w, acc2[r]))))))));
        }
      }

      // LSTM pointwise for dims d=tid and d=tid+256
      #pragma unroll
      for (int p=0;p<2;p++) {
        float xi = acc2[0+p] + ghv[0+p];
        float xf = acc2[2+p] + ghv[2+p];
        float xg = acc2[4+p] + ghv[4+p];
        float xo = acc2[6+p] + ghv[6+p];
        float c = sigmoid_fast(xf)*c_reg[p] + sigmoid_fast(xi)*tanh_fast(xg);
        c_reg[p] = c;
        hs[tid + 256*p] = sigmoid_fast(xo) * tanh_fast(c);
      }
      __syncthreads();
      // pack h_{t+1} as bf16 pairs, coherent store
      {
        u32 pk = (u32)f2bf(hs[2*tid]) | ((u32)f2bf(hs[2*tid+1]) << 16);
        st_u(H32 + (size_t)(t+1)*16384 + b*256 + tid, pk);
      }
    }
    if (t < 30) { gen++; gbar2(flags, bid, gen); }
  }
}

// ---------------- workspace offsets (bytes, 256-aligned) ----------------
#define OFF_FLG  0u              // 512        flags (zeroed per call)
#define OFF_H    1024u           // 2,097,152  bf16 (32,64,512); slot0 zeroed
#define OFF_UV   2098176u        // 6,422,528  bf16 (64,196,256)
#define OFF_X    8520704u        // 1,015,808  bf16 (1984,256)
#define OFF_XG   9536512u        // 16,252,928 f32  (31,64,2048)
#define OFF_GH   25789440u       // 524,288    f32  (64,2048)
#define OFF_WH   26313728u       // 65,536     f32  (64,256)
#define OFF_E    26379264u       // 1,015,808  bf16 (1984,256)
#define OFF_VB   27395072u       // 3,211,264  bf16 V (pre-decoder); reused as Wf f32 1MB (decoder)
#define OFF_EMB  30606336u       // 15,360,000 bf16 embed
#define OFF_WIH  45966336u       // 1,572,864  bf16 Wih
#define OFF_WHH  47539200u       // 2,097,152  bf16 Whh
#define OFF_AWW  49636352u       // 262,144    bf16 attWw
#define OFF_AUW  49898496u       // 65,536     bf16 attUw
#define OFF_PRJ  49964032u       // 262,144    bf16 projw  -> end 50,226,176

extern "C" void kernel_launch(void* const* d_in, const int* in_sizes, int n_in,
                              void* d_out, int out_size, void* d_ws, size_t ws_size,
                              hipStream_t stream)
{
  const float* V      = (const float*)d_in[0];
  const int*   y      = (const int*)  d_in[1];
  const float* embed  = (const float*)d_in[2];
  const float* attWw  = (const float*)d_in[3];
  const float* attWb  = (const float*)d_in[4];
  const float* attUw  = (const float*)d_in[5];
  const float* attUb  = (const float*)d_in[6];
  const float* attvw  = (const float*)d_in[7];
  const float* attvb  = (const float*)d_in[8];
  const float* Wih    = (const float*)d_in[9];
  const float* Whh    = (const float*)d_in[10];
  const float* bih    = (const float*)d_in[11];
  const float* bhh    = (const float*)d_in[12];
  const float* projw  = (const float*)d_in[13];
  float* out = (float*)d_out;
  char* ws = (char*)d_ws;

  u32*   flags = (u32*) (ws + OFF_FLG);
  u16*   H    = (u16*)  (ws + OFF_H);
  u16*   UVb  = (u16*)  (ws + OFF_UV);
  u16*   Xb   = (u16*)  (ws + OFF_X);
  float* Xg   = (float*)(ws + OFF_XG);
  float* gh   = (float*)(ws + OFF_GH);
  float* wh   = (float*)(ws + OFF_WH);
  u16*   E    = (u16*)  (ws + OFF_E);
  u16*   Vb   = (u16*)  (ws + OFF_VB);
  float* Wf   = (float*)(ws + OFF_VB);   // reuses Vb space after UV gemm
  u16*   embB = (u16*)  (ws + OFF_EMB);
  u16*   WihB = (u16*)  (ws + OFF_WIH);
  u16*   WhhB = (u16*)  (ws + OFF_WHH);
  u16*   attWwB = (u16*)(ws + OFF_AWW);
  u16*   attUwB = (u16*)(ws + OFF_AUW);
  u16*   projB  = (u16*)(ws + OFF_PRJ);

  // zero flags + H slot 0 (h0 = 0) — re-done every call (ws is re-poisoned)
  hipMemsetAsync(ws, 0, 1024 + 65536, stream);

  // f32 -> bf16 conversions for MFMA operands
  f2b_kernel<<<(401408+255)/256, 256, 0, stream>>>(V,     Vb,     401408);
  f2b_kernel<<<(1920000+255)/256,256, 0, stream>>>(embed, embB,  1920000);
  f2b_kernel<<<(196608+255)/256, 256, 0, stream>>>(Wih,   WihB,   196608);
  f2b_kernel<<<(262144+255)/256, 256, 0, stream>>>(Whh,   WhhB,   262144);
  f2b_kernel<<<(32768+255)/256,  256, 0, stream>>>(attWw, attWwB,  32768);
  f2b_kernel<<<(8192+255)/256,   256, 0, stream>>>(attUw, attUwB,   8192);
  f2b_kernel<<<(32768+255)/256,  256, 0, stream>>>(projw, projB,   32768);

  gather_x<<<1984, 256, 0, stream>>>(y, embed, Xb);

  // UV = V @ attUw^T + attUb  (bf16 out)   M=12544 N=256 K=128
  gemm_bt<<<196*2, 256, 0, stream>>>(Vb, 128, attUwB, 128, attUb, nullptr,
                                     UVb, 256, 12544, 256, 128, 196, 1);
  // Wf = Wih[:,256:384] f32 (overwrites Vb region — stream-ordered after UV gemm)
  prep_wih2f<<<1024, 256, 0, stream>>>(Wih, Wf);
  // Xg = X @ Wih[:, :256]^T + bih + bhh  (f32 out)   M=1984 N=2048 K=256
  gemm_bt<<<31*16, 256, 0, stream>>>(Xb, 256, WihB, 384, bih, bhh,
                                     Xg, 2048, 1984, 2048, 256, 31, 0);

  decoder_steps<<<NB, 256, 0, stream>>>(V, attWb, attvw, attvb,
      WhhB, attWwB, Wf, (u32*)H, UVb, Xg, gh, wh, flags);

  // E = H[1..31] @ projw^T (bf16 out)   M=1984 N=256 K=512
  gemm_bt<<<31*2, 256, 0, stream>>>(H + 32768, 512, projB, 512, nullptr, nullptr,
                                    E, 256, 1984, 256, 512, 31, 1);
  // logits = E @ embed^T -> d_out f32 with (s,b)->(b,s) row remap   M=1984 N=30000 K=256
  gemm_bt<<<31*235, 256, 0, stream>>>(E, 256, embB, 256, nullptr, nullptr,
                                      out, 30000, 1984, 30000, 256, 31, 2);
}

// Round 4
// 2504.349 us; speedup vs baseline: 1.6239x; 1.1243x over previous
//
#include <hip/hip_runtime.h>
#include <stdint.h>

typedef unsigned short u16;
typedef uint32_t u32;
typedef short s16x8 __attribute__((ext_vector_type(8)));
typedef float f32x4 __attribute__((ext_vector_type(4)));

#define DEV __device__ __forceinline__

DEV float bf2f(u16 h){ union{u32 u; float f;} x; x.u = ((u32)h)<<16; return x.f; }
DEV u16 f2bf(float f){ union{float f; u32 u;} x; x.f = f; u32 u = x.u;
  return (u16)((u + 0x7fffu + ((u>>16)&1u))>>16); }

DEV float tanh_fast(float x){
  x = fminf(3.2f, fmaxf(-3.2f, x));
  float s = x*x;
  float n = x * fmaf(s, fmaf(s, (s + 378.0f), 17325.0f), 135135.0f);
  float d = fmaf(s, fmaf(s, fmaf(s, 28.0f, 3150.0f), 62370.0f), 135135.0f);
  return __fdividef(n, d);
}
DEV float sigmoid_fast(float x){ return __fdividef(1.0f, 1.0f + __expf(-x)); }

// device-coherent (agent-scope, write-through) accessors — STORES + flags only.
// Consumers read exchange data with PLAIN loads; correctness comes from
// time-slicing (every exchange address is written once and read once, so no
// consumer cache can hold a stale copy).
DEV void  st_f(float* p, float v){ __hip_atomic_store(p, v, __ATOMIC_RELAXED, __HIP_MEMORY_SCOPE_AGENT); }
DEV u32   ld_u(const u32* p){ return __hip_atomic_load(p, __ATOMIC_RELAXED, __HIP_MEMORY_SCOPE_AGENT); }
DEV void  st_u(u32* p, u32 v){ __hip_atomic_store(p, v, __ATOMIC_RELAXED, __HIP_MEMORY_SCOPE_AGENT); }

// ---------------- f32 -> bf16 bulk convert (n % 4 == 0) ----------------
__global__ void f2b_kernel(const float* __restrict__ src, u16* __restrict__ dst, int n4){
  int i = blockIdx.x*blockDim.x + threadIdx.x;
  if (i < n4) {
    float4 v = ((const float4*)src)[i];
    ushort4 o; o.x = f2bf(v.x); o.y = f2bf(v.y); o.z = f2bf(v.z); o.w = f2bf(v.w);
    ((ushort4*)dst)[i] = o;
  }
}

// ---- extract Wih[:,256:384] as f32 (2048 x 128) ----
__global__ void prep_wih2f(const float* __restrict__ Wih, float* __restrict__ Wf){
  int idx = blockIdx.x*256 + threadIdx.x;      // 2048*128 = 262144
  int j = idx>>7, k = idx&127;
  Wf[idx] = Wih[(size_t)j*384 + 256 + k];
}

// ---------------- generic C = A * B^T (+bias) bf16 MFMA GEMM ----------------
// mode 0: f32 out; 1: bf16 out; 2: f32 out with row remap (r=s*64+b -> b*31+s)
__global__ __launch_bounds__(256) void gemm_bt(
    const u16* __restrict__ A, int lda,
    const u16* __restrict__ B, int ldb,
    const float* __restrict__ bias1, const float* __restrict__ bias2,
    void* __restrict__ C, int ldc,
    int M, int N, int K, int Mt, int mode)
{
  __shared__ __align__(16) u16 As[64*64];
  __shared__ __align__(16) u16 Bs[128*64];
  int mt = blockIdx.x % Mt, nt = blockIdx.x / Mt;
  int m0 = mt*64, n0 = nt*128;
  int tid = threadIdx.x, wave = tid>>6, lane = tid&63;
  int lrow = lane>>3, lcol = (lane&7)*8;
  f32x4 acc[2][4];
  #pragma unroll
  for (int i=0;i<2;i++)
    #pragma unroll
    for (int j=0;j<4;j++) acc[i][j] = (f32x4){0,0,0,0};
  int wm = (wave>>1)*32, wn = (wave&1)*64;
  int fr = lane&15, fk = (lane>>4)*8;
  for (int k0 = 0; k0 < K; k0 += 64) {
    __syncthreads();
    #pragma unroll
    for (int i = 0; i < 2; i++) {
      int ci = wave + i*4;
      int row = ci*8 + lrow;
      const u16* g = A + (size_t)(m0+row)*lda + k0 + lcol;
      __builtin_amdgcn_global_load_lds(
        (const __attribute__((address_space(1))) u32*)g,
        (__attribute__((address_space(3))) u32*)&As[ci*512], 16, 0, 0);
    }
    #pragma unroll
    for (int i = 0; i < 4; i++) {
      int ci = wave + i*4;
      int row = ci*8 + lrow;
      int gr = n0 + row; gr = gr < N ? gr : N-1;
      const u16* g = B + (size_t)gr*ldb + k0 + lcol;
      __builtin_amdgcn_global_load_lds(
        (const __attribute__((address_space(1))) u32*)g,
        (__attribute__((address_space(3))) u32*)&Bs[ci*512], 16, 0, 0);
    }
    __syncthreads();
    #pragma unroll
    for (int kk = 0; kk < 2; kk++) {
      s16x8 af[2], bfv[4];
      #pragma unroll
      for (int mi=0; mi<2; mi++)
        af[mi] = *(const s16x8*)&As[(wm + mi*16 + fr)*64 + kk*32 + fk];
      #pragma unroll
      for (int ni=0; ni<4; ni++)
        bfv[ni] = *(const s16x8*)&Bs[(wn + ni*16 + fr)*64 + kk*32 + fk];
      #pragma unroll
      for (int mi=0; mi<2; mi++)
        #pragma unroll
        for (int ni=0; ni<4; ni++)
          acc[mi][ni] = __builtin_amdgcn_mfma_f32_16x16x32_bf16(af[mi], bfv[ni], acc[mi][ni], 0,0,0);
    }
  }
  #pragma unroll
  for (int mi=0; mi<2; mi++)
    #pragma unroll
    for (int ni=0; ni<4; ni++) {
      int col = n0 + wn + ni*16 + (lane&15);
      if (col >= N) continue;
      float bv = 0.0f;
      if (bias1) bv += bias1[col];
      if (bias2) bv += bias2[col];
      int rbase = m0 + wm + mi*16 + ((lane>>4)<<2);
      #pragma unroll
      for (int r=0; r<4; r++) {
        int row = rbase + r;
        float v = acc[mi][ni][r] + bv;
        if (mode == 0) ((float*)C)[(size_t)row*ldc + col] = v;
        else if (mode == 1) ((u16*)C)[(size_t)row*ldc + col] = f2bf(v);
        else { int orow = (row&63)*31 + (row>>6); ((float*)C)[(size_t)orow*ldc + col] = v; }
      }
    }
}

// ---------- token embedding gather: X[s*64+b][e] = bf16(embed[y[b][s]][e]) ----------
__global__ void gather_x(const int* __restrict__ y, const float* __restrict__ embed, u16* __restrict__ X)
{
  int r = blockIdx.x;
  int s = r>>6, b = r&63;
  int tok = y[b*32 + s];
  X[(size_t)r*256 + threadIdx.x] = f2bf(embed[(size_t)tok*256 + threadIdx.x]);
}

// ---------------- persistent recurrence kernel (72 blocks, flag barrier) ----------------
#define NB 72

// all-report flag barrier: producers drain their write-through stores
// (s_waitcnt 0) before posting; consumers poll all 72 flags with coherent
// scalar loads. No fences, no L2 writeback/invalidate anywhere.
DEV void gbar2(u32* flags, int bid, unsigned g){
  __asm__ volatile("" ::: "memory");
  __builtin_amdgcn_s_waitcnt(0);
  __syncthreads();
  if (threadIdx.x == 0) st_u(&flags[bid], g);
  if (threadIdx.x < 64) {
    bool done = false;
    while (!done) {
      u32 a = ld_u(&flags[threadIdx.x]);
      u32 b = (threadIdx.x < 8) ? ld_u(&flags[64+threadIdx.x]) : g;
      done = __all(a >= g && b >= g);
      if (!done) __builtin_amdgcn_s_sleep(1);
    }
  }
  __syncthreads();
  __asm__ volatile("" ::: "memory");
}

__global__ __launch_bounds__(256) void decoder_steps(
    const float* __restrict__ V,     // (64,196,128) f32, cached
    const float* __restrict__ attWb, // (256) f32, cached
    const float* __restrict__ attvw, // (256) f32, cached
    const float* __restrict__ attvb, // (1)
    const u16* __restrict__ WhhB,    // (2048,512) bf16, cached
    const u16* __restrict__ attWwB,  // (256,512) bf16, cached
    const float* __restrict__ Wf,    // (2048,128) f32 = Wih[:,256:384], cached
    u16* __restrict__ H,             // (32,64,512) bf16, time-sliced exchange
    const u16* __restrict__ UV,      // (64,196,256) bf16, cached
    const u16* __restrict__ Xg,      // (31,64,2048) bf16, cached (prior kernel)
    float* __restrict__ gh,          // (31,64,2048) f32, time-sliced exchange
    float* __restrict__ wh,          // (31,64,256) f32, time-sliced exchange
    u32* __restrict__ flags)
{
  int bid = blockIdx.x, tid = threadIdx.x;
  int wave = tid>>6, lane = tid&63;
  int fr = lane&15, fkq = lane>>4;

  __shared__ float whs[256];
  __shared__ float vws[256];
  __shared__ float esc[200];
  __shared__ float red[2];
  __shared__ float part[256];
  __shared__ float ctxf[128];
  __shared__ float hs[512];

  float c_reg[2] = {0.f, 0.f};
  float vb = attvb[0];
  unsigned gen = 0;

  // per-block P1 weight base (block handles 32 consecutive rows of [Whh ; attWw])
  const u16* Wbase = (bid < 64) ? (WhhB + (size_t)bid*32*512)
                                : (attWwB + (size_t)(bid-64)*32*512);

  for (int t = 0; t < 31; t++) {
    // ---- P1: [gh | wh] = h_t @ [W_hh ; att_W_w]^T (+Xg | +att_W_b) ----
    {
      const u16* Hrow = H + (size_t)t*32768 + (wave*16 + fr)*512;  // plain loads
      f32x4 acc0 = (f32x4){0,0,0,0}, acc1 = (f32x4){0,0,0,0};
      #pragma unroll 4
      for (int ks = 0; ks < 16; ks++) {
        int kidx = ks*32 + fkq*8;
        s16x8 af = *(const s16x8*)&Hrow[kidx];
        s16x8 b0 = *(const s16x8*)&Wbase[(size_t)(fr)*512 + kidx];
        s16x8 b1 = *(const s16x8*)&Wbase[(size_t)(16+fr)*512 + kidx];
        acc0 = __builtin_amdgcn_mfma_f32_16x16x32_bf16(af, b0, acc0, 0,0,0);
        acc1 = __builtin_amdgcn_mfma_f32_16x16x32_bf16(af, b1, acc1, 0,0,0);
      }
      int col = lane&15;
      int rb = wave*16 + fkq*4;
      if (bid < 64) {
        float* ghs = gh + (size_t)t*131072;
        const u16* xgs = Xg + (size_t)t*131072;
        #pragma unroll
        for (int ntile=0; ntile<2; ntile++) {
          int j = bid*32 + ntile*16 + col;
          f32x4 a = ntile ? acc1 : acc0;
          #pragma unroll
          for (int r=0;r<4;r++){
            int b = rb + r;
            st_f(&ghs[b*2048 + j], a[r] + bf2f(xgs[b*2048 + j]));
          }
        }
      } else {
        float* whsl = wh + (size_t)t*16384;
        #pragma unroll
        for (int ntile=0; ntile<2; ntile++) {
          int a_ = (bid-64)*32 + ntile*16 + col;
          float wbv = attWb[a_];
          f32x4 a = ntile ? acc1 : acc0;
          #pragma unroll
          for (int r=0;r<4;r++){
            int b = rb + r;
            st_f(&whsl[b*256 + a_], a[r] + wbv);
          }
        }
      }
    }
    gen++; gbar2(flags, bid, gen);

    // ---- P2': per-batch block: scores -> softmax -> ctx -> ctx-gates -> LSTM pointwise ----
    if (bid < 64) {
      int b = bid;
      // plain loads of this step's exchange slices (fresh addresses -> no staleness)
      const float* ghs = gh + (size_t)t*131072 + b*2048;
      float ghv[8];
      #pragma unroll
      for (int r=0;r<8;r++) ghv[r] = ghs[tid + 256*r];
      whs[tid] = wh[(size_t)t*16384 + b*256 + tid];
      vws[tid] = attvw[tid];
      __syncthreads();

      // scores: thread n computes e[n] over 256 attention dims
      if (tid < 196) {
        const u16* uvrow = UV + ((size_t)b*196 + tid)*256;
        float e = 0.0f;
        for (int a8 = 0; a8 < 256; a8 += 8) {
          s16x8 u8 = *(const s16x8*)&uvrow[a8];
          #pragma unroll
          for (int j=0;j<8;j++)
            e = fmaf(vws[a8+j], tanh_fast(whs[a8+j] + bf2f((u16)u8[j])), e);
        }
        esc[tid] = e + vb;
      }
      __syncthreads();
      if (tid < 64) {
        float m = fmaxf(esc[tid], esc[64+tid]);
        if (tid < 68) m = fmaxf(m, esc[128+tid]);
        if (tid < 4)  m = fmaxf(m, esc[192+tid]);
        #pragma unroll
        for (int off=32; off>=1; off>>=1) m = fmaxf(m, __shfl_xor(m, off));
        if (tid==0) red[0] = m;
      }
      __syncthreads();
      float mx = red[0];
      if (tid < 196) esc[tid] = __expf(esc[tid] - mx);
      __syncthreads();
      if (tid < 64) {
        float s = esc[tid] + esc[64+tid];
        if (tid < 68) s += esc[128+tid];
        if (tid < 4)  s += esc[192+tid];
        #pragma unroll
        for (int off=32; off>=1; off>>=1) s += __shfl_xor(s, off);
        if (tid==0) red[1] = s;
      }
      __syncthreads();
      float inv = __fdividef(1.0f, red[1]);

      // ctx: two n-halves in parallel, combine
      {
        int k = tid&127, hf = tid>>7;
        const float* vp = V + ((size_t)b*196 + hf*98)*128 + k;
        float a = 0.f;
        for (int n2=0; n2<98; n2++) a = fmaf(esc[hf*98+n2], vp[(size_t)n2*128], a);
        part[tid] = a;
      }
      __syncthreads();
      if (tid < 128) ctxf[tid] = (part[tid] + part[128+tid]) * inv;
      __syncthreads();

      // ctx-gates: thread handles rows j = tid + 256*r, r=0..7  (f32 weights)
      float acc2[8] = {0,0,0,0,0,0,0,0};
      for (int q0=0; q0<128; q0+=8) {
        float cx[8];
        *(float4*)&cx[0] = *(const float4*)&ctxf[q0];
        *(float4*)&cx[4] = *(const float4*)&ctxf[q0+4];
        #pragma unroll
        for (int r=0;r<8;r++){
          const float4* wp = (const float4*)&Wf[(size_t)(tid+256*r)*128 + q0];
          float4 w0 = wp[0], w1 = wp[1];
          acc2[r] = fmaf(cx[0],w0.x, fmaf(cx[1],w0.y, fmaf(cx[2],w0.z, fmaf(cx[3],w0.w,
                    fmaf(cx[4],w1.x, fmaf(cx[5],w1.y, fmaf(cx[6],w1.z, fmaf(cx[7],w1.w, acc2[r]))))))));
        }
      }

      // LSTM pointwise for dims d=tid and d=tid+256
      #pragma unroll
      for (int p=0;p<2;p++) {
        float xi = acc2[0+p] + ghv[0+p];
        float xf = acc2[2+p] + ghv[2+p];
        float xg = acc2[4+p] + ghv[4+p];
        float xo = acc2[6+p] + ghv[6+p];
        float c = sigmoid_fast(xf)*c_reg[p] + sigmoid_fast(xi)*tanh_fast(xg);
        c_reg[p] = c;
        hs[tid + 256*p] = sigmoid_fast(xo) * tanh_fast(c);
      }
      __syncthreads();
      // pack h_{t+1} as bf16 pairs, write-through store
      {
        u32 pk = (u32)f2bf(hs[2*tid]) | ((u32)f2bf(hs[2*tid+1]) << 16);
        st_u((u32*)H + (size_t)(t+1)*16384 + b*256 + tid, pk);
      }
    }
    if (t < 30) { gen++; gbar2(flags, bid, gen); }
  }
}

// ---------------- workspace offsets (bytes, 256-aligned) ----------------
#define OFF_FLG  0u              // 1,024      flags (zeroed per call)
#define OFF_H    1024u           // 2,097,152  bf16 (32,64,512); slot0 zeroed
#define OFF_UV   2098176u        // 6,422,528  bf16 (64,196,256)
#define OFF_X    8520704u        // 1,015,808  bf16 (1984,256)
#define OFF_XG   9536512u        // 8,126,464  bf16 (31,64,2048)
#define OFF_GH   17662976u       // 16,252,928 f32  (31,64,2048); embB overlaid post-decoder
#define OFF_EMB  OFF_GH          // 15,360,000 bf16 embed (after decoder_steps)
#define OFF_WH   33915904u       // 2,031,616  f32  (31,64,256)
#define OFF_E    35947520u       // 1,015,808  bf16 (1984,256)
#define OFF_VB   36963328u       // 3,211,264  bf16 V (pre-decoder); Wf f32 1MB overlay
#define OFF_WIH  40174592u       // 1,572,864  bf16 Wih
#define OFF_WHH  41747456u       // 2,097,152  bf16 Whh
#define OFF_AWW  43844608u       // 262,144    bf16 attWw
#define OFF_AUW  44106752u       // 65,536     bf16 attUw
#define OFF_PRJ  44172288u       // 262,144    bf16 projw  -> end 44,434,432

extern "C" void kernel_launch(void* const* d_in, const int* in_sizes, int n_in,
                              void* d_out, int out_size, void* d_ws, size_t ws_size,
                              hipStream_t stream)
{
  const float* V      = (const float*)d_in[0];
  const int*   y      = (const int*)  d_in[1];
  const float* embed  = (const float*)d_in[2];
  const float* attWw  = (const float*)d_in[3];
  const float* attWb  = (const float*)d_in[4];
  const float* attUw  = (const float*)d_in[5];
  const float* attUb  = (const float*)d_in[6];
  const float* attvw  = (const float*)d_in[7];
  const float* attvb  = (const float*)d_in[8];
  const float* Wih    = (const float*)d_in[9];
  const float* Whh    = (const float*)d_in[10];
  const float* bih    = (const float*)d_in[11];
  const float* bhh    = (const float*)d_in[12];
  const float* projw  = (const float*)d_in[13];
  float* out = (float*)d_out;
  char* ws = (char*)d_ws;

  u32*   flags = (u32*) (ws + OFF_FLG);
  u16*   H    = (u16*)  (ws + OFF_H);
  u16*   UVb  = (u16*)  (ws + OFF_UV);
  u16*   Xb   = (u16*)  (ws + OFF_X);
  u16*   Xg   = (u16*)  (ws + OFF_XG);
  float* gh   = (float*)(ws + OFF_GH);
  float* wh   = (float*)(ws + OFF_WH);
  u16*   E    = (u16*)  (ws + OFF_E);
  u16*   Vb   = (u16*)  (ws + OFF_VB);
  float* Wf   = (float*)(ws + OFF_VB);   // reuses Vb space after UV gemm
  u16*   embB = (u16*)  (ws + OFF_EMB);  // reuses gh space after decoder
  u16*   WihB = (u16*)  (ws + OFF_WIH);
  u16*   WhhB = (u16*)  (ws + OFF_WHH);
  u16*   attWwB = (u16*)(ws + OFF_AWW);
  u16*   attUwB = (u16*)(ws + OFF_AUW);
  u16*   projB  = (u16*)(ws + OFF_PRJ);

  // zero flags + H slot 0 (h0 = 0) — re-done every call (ws is re-poisoned)
  hipMemsetAsync(ws, 0, 1024 + 65536, stream);

  // f32 -> bf16 conversions for MFMA operands (embed deferred until after decoder)
  f2b_kernel<<<(401408+255)/256, 256, 0, stream>>>(V,     Vb,     401408);
  f2b_kernel<<<(196608+255)/256, 256, 0, stream>>>(Wih,   WihB,   196608);
  f2b_kernel<<<(262144+255)/256, 256, 0, stream>>>(Whh,   WhhB,   262144);
  f2b_kernel<<<(32768+255)/256,  256, 0, stream>>>(attWw, attWwB,  32768);
  f2b_kernel<<<(8192+255)/256,   256, 0, stream>>>(attUw, attUwB,   8192);
  f2b_kernel<<<(32768+255)/256,  256, 0, stream>>>(projw, projB,   32768);

  gather_x<<<1984, 256, 0, stream>>>(y, embed, Xb);

  // UV = V @ attUw^T + attUb  (bf16 out)   M=12544 N=256 K=128
  gemm_bt<<<196*2, 256, 0, stream>>>(Vb, 128, attUwB, 128, attUb, nullptr,
                                     UVb, 256, 12544, 256, 128, 196, 1);
  // Wf = Wih[:,256:384] f32 (overwrites Vb region — stream-ordered after UV gemm)
  prep_wih2f<<<1024, 256, 0, stream>>>(Wih, Wf);
  // Xg = X @ Wih[:, :256]^T + bih + bhh  (bf16 out)   M=1984 N=2048 K=256
  gemm_bt<<<31*16, 256, 0, stream>>>(Xb, 256, WihB, 384, bih, bhh,
                                     Xg, 2048, 1984, 2048, 256, 31, 1);

  decoder_steps<<<NB, 256, 0, stream>>>(V, attWb, attvw, attvb,
      WhhB, attWwB, Wf, H, UVb, Xg, gh, wh, flags);

  // embed -> bf16 (overlays dead gh region; runs after decoder completes)
  f2b_kernel<<<(1920000+255)/256, 256, 0, stream>>>(embed, embB, 1920000);

  // E = H[1..31] @ projw^T (bf16 out)   M=1984 N=256 K=512
  gemm_bt<<<31*2, 256, 0, stream>>>(H + 32768, 512, projB, 512, nullptr, nullptr,
                                    E, 256, 1984, 256, 512, 31, 1);
  // logits = E @ embed^T -> d_out f32 with (s,b)->(b,s) row remap   M=1984 N=30000 K=256
  gemm_bt<<<31*235, 256, 0, stream>>>(E, 256, embB, 256, nullptr, nullptr,
                                      out, 30000, 1984, 30000, 256, 31, 2);
}